// Round 1
// baseline (110.247 us; speedup 1.0000x reference)
//
#include <hip/hip_runtime.h>
#include <math.h>

#define HID 32
#define EPSF 1e-8f

__device__ __forceinline__ float wave_red64(float v) {
#pragma unroll
    for (int off = 32; off > 0; off >>= 1) v += __shfl_down(v, off);
    return v;
}

__device__ __forceinline__ float sigmf(float x) { return 1.0f / (1.0f + expf(-x)); }

// Kernel 1: fused 4-way reduction over grad/param. Writes per-block partials
// (4 floats per block) to ws. Deterministic tree reduction, no atomics.
__global__ __launch_bounds__(256) void lb_reduce(
    const float4* __restrict__ g4, const float4* __restrict__ p4,
    float* __restrict__ partials, int n4)
{
    float sg2 = 0.f, sp2 = 0.f, sgp = 0.f, ssl = 0.f;
    int stride = gridDim.x * blockDim.x;
    for (int i = blockIdx.x * blockDim.x + threadIdx.x; i < n4; i += stride) {
        float4 g = g4[i];
        float4 p = p4[i];
        sg2 = fmaf(g.x, g.x, fmaf(g.y, g.y, fmaf(g.z, g.z, fmaf(g.w, g.w, sg2))));
        sp2 = fmaf(p.x, p.x, fmaf(p.y, p.y, fmaf(p.z, p.z, fmaf(p.w, p.w, sp2))));
        sgp = fmaf(g.x, p.x, fmaf(g.y, p.y, fmaf(g.z, p.z, fmaf(g.w, p.w, sgp))));
        // sign(g)*log1p(|g|); copysign handles g==±0 (log1p(0)=0 -> ±0, sum unaffected)
        ssl += copysignf(log1pf(fabsf(g.x)), g.x)
             + copysignf(log1pf(fabsf(g.y)), g.y)
             + copysignf(log1pf(fabsf(g.z)), g.z)
             + copysignf(log1pf(fabsf(g.w)), g.w);
    }
    sg2 = wave_red64(sg2);
    sp2 = wave_red64(sp2);
    sgp = wave_red64(sgp);
    ssl = wave_red64(ssl);
    __shared__ float sh[4][4];
    int wid = threadIdx.x >> 6;
    if ((threadIdx.x & 63) == 0) {
        sh[0][wid] = sg2; sh[1][wid] = sp2; sh[2][wid] = sgp; sh[3][wid] = ssl;
    }
    __syncthreads();
    if (threadIdx.x == 0) {
        float* out = partials + (size_t)blockIdx.x * 4;
        out[0] = sh[0][0] + sh[0][1] + sh[0][2] + sh[0][3];
        out[1] = sh[1][0] + sh[1][1] + sh[1][2] + sh[1][3];
        out[2] = sh[2][0] + sh[2][1] + sh[2][2] + sh[2][3];
        out[3] = sh[3][0] + sh[3][1] + sh[3][2] + sh[3][3];
    }
}

// Kernel 2: single block. Reduce partials -> features -> LSTM cell -> heads -> mult.
__global__ __launch_bounds__(256) void lb_finish(
    const float* __restrict__ partials, int nblk,
    const float* __restrict__ neuromod, const float* __restrict__ comp_delta,
    const float* __restrict__ m_prev, const float* __restrict__ h_prev,
    const float* __restrict__ c_prev,
    const float* __restrict__ W_ih, const float* __restrict__ W_hh,
    const float* __restrict__ b_ih, const float* __restrict__ b_hh,
    const float* __restrict__ Ws, const float* __restrict__ bs,
    const float* __restrict__ Wg1, const float* __restrict__ bg1,
    const float* __restrict__ Wg2, const float* __restrict__ bg2,
    float* __restrict__ out, float inv_n)
{
    __shared__ float feat[10];
    __shared__ float gates[4 * HID];
    __shared__ float hnew[HID];
    __shared__ float hidv[HID / 2];
    __shared__ float shred[4][4];

    // ---- reduce per-block partials ----
    float s0 = 0.f, s1 = 0.f, s2 = 0.f, s3 = 0.f;
    for (int i = threadIdx.x; i < nblk; i += blockDim.x) {
        const float* p = partials + (size_t)i * 4;
        s0 += p[0]; s1 += p[1]; s2 += p[2]; s3 += p[3];
    }
    s0 = wave_red64(s0); s1 = wave_red64(s1); s2 = wave_red64(s2); s3 = wave_red64(s3);
    int wid = threadIdx.x >> 6;
    if ((threadIdx.x & 63) == 0) {
        shred[0][wid] = s0; shred[1][wid] = s1; shred[2][wid] = s2; shred[3][wid] = s3;
    }
    __syncthreads();

    if (threadIdx.x == 0) {
        float sum_g2 = shred[0][0] + shred[0][1] + shred[0][2] + shred[0][3];
        float sum_p2 = shred[1][0] + shred[1][1] + shred[1][2] + shred[1][3];
        float sum_gp = shred[2][0] + shred[2][1] + shred[2][2] + shred[2][3];
        float sum_sl = shred[3][0] + shred[3][1] + shred[3][2] + shred[3][3];
        float g_norm = fmaxf(sqrtf(sum_g2), EPSF);
        float p_norm = fmaxf(sqrtf(sum_p2), EPSF);
        feat[0] = logf(g_norm + EPSF);
        feat[1] = logf(p_norm + EPSF);
        feat[2] = sum_gp / (g_norm * p_norm + EPSF);
        feat[3] = sum_sl * inv_n;
        feat[4] = 0.9f * m_prev[0] + (1.0f - 0.9f) * g_norm;  // momentum
        feat[5] = comp_delta[0];
        feat[6] = neuromod[0];
        feat[7] = neuromod[1];
        feat[8] = neuromod[2];
        feat[9] = neuromod[3];
    }
    __syncthreads();

    // ---- LSTM gates: gates[r] = W_ih[r,:]@feat + b_ih[r] + W_hh[r,:]@h_prev + b_hh[r]
    if (threadIdx.x < 4 * HID) {
        int r = threadIdx.x;
        float acc = b_ih[r] + b_hh[r];
#pragma unroll
        for (int k = 0; k < 10; ++k) acc = fmaf(W_ih[r * 10 + k], feat[k], acc);
#pragma unroll
        for (int k = 0; k < HID; ++k) acc = fmaf(W_hh[r * HID + k], h_prev[k], acc);
        gates[r] = acc;
    }
    __syncthreads();

    // ---- cell/state update (torch gate order i, f, g, o) ----
    if (threadIdx.x < HID) {
        int j = threadIdx.x;
        float iv = sigmf(gates[j]);
        float fv = sigmf(gates[HID + j]);
        float gv = tanhf(gates[2 * HID + j]);
        float ov = sigmf(gates[3 * HID + j]);
        float c = fv * c_prev[j] + iv * gv;
        hnew[j] = ov * tanhf(c);
    }
    __syncthreads();

    // ---- gate head hidden layer ----
    if (threadIdx.x < HID / 2) {
        int k = threadIdx.x;
        float a = bg1[k];
#pragma unroll
        for (int j = 0; j < HID; ++j) a = fmaf(Wg1[k * HID + j], hnew[j], a);
        hidv[k] = tanhf(a);
    }
    __syncthreads();

    // ---- final heads + clip ----
    if (threadIdx.x == 0) {
        float rs = bs[0];
#pragma unroll
        for (int j = 0; j < HID; ++j) rs = fmaf(Ws[j], hnew[j], rs);
        float scale = expf(tanhf(rs));
        float cg = bg2[0];
#pragma unroll
        for (int k = 0; k < HID / 2; ++k) cg = fmaf(Wg2[k], hidv[k], cg);
        float comp_g = sigmf(cg);
        float mult = scale * (0.5f + comp_g);
        mult = fminf(fmaxf(mult, 0.01f), 10.0f);
        out[0] = mult;
    }
}

extern "C" void kernel_launch(void* const* d_in, const int* in_sizes, int n_in,
                              void* d_out, int out_size, void* d_ws, size_t ws_size,
                              hipStream_t stream) {
    const float* grad       = (const float*)d_in[0];
    const float* param      = (const float*)d_in[1];
    const float* neuromod   = (const float*)d_in[2];
    const float* comp_delta = (const float*)d_in[3];
    const float* m_prev     = (const float*)d_in[4];
    const float* h_prev     = (const float*)d_in[5];
    const float* c_prev     = (const float*)d_in[6];
    const float* W_ih       = (const float*)d_in[7];
    const float* W_hh       = (const float*)d_in[8];
    const float* b_ih       = (const float*)d_in[9];
    const float* b_hh       = (const float*)d_in[10];
    const float* Ws         = (const float*)d_in[11];
    const float* bs         = (const float*)d_in[12];
    const float* Wg1        = (const float*)d_in[13];
    const float* bg1        = (const float*)d_in[14];
    const float* Wg2        = (const float*)d_in[15];
    const float* bg2        = (const float*)d_in[16];

    int n = in_sizes[0];            // 33554432
    int n4 = n / 4;                 // float4 count (4096*8192 divisible by 4)

    int nblk = 2048;                // 2048 blocks * 256 thr = 32 waves/CU
    size_t need = (size_t)nblk * 4 * sizeof(float);
    if (ws_size < need) {           // defensive: shrink if scratch is small
        nblk = (int)(ws_size / (4 * sizeof(float)));
        if (nblk < 1) nblk = 1;
    }
    float* partials = (float*)d_ws;

    lb_reduce<<<nblk, 256, 0, stream>>>((const float4*)grad, (const float4*)param,
                                        partials, n4);
    lb_finish<<<1, 256, 0, stream>>>(partials, nblk,
                                     neuromod, comp_delta, m_prev, h_prev, c_prev,
                                     W_ih, W_hh, b_ih, b_hh, Ws, bs,
                                     Wg1, bg1, Wg2, bg2,
                                     (float*)d_out, 1.0f / (float)n);
}

// Round 2
// 53.226 us; speedup vs baseline: 2.0713x; 2.0713x over previous
//
#include <hip/hip_runtime.h>
#include <math.h>

#define HID 32
#define EPSF 1e-8f
#define LN2F 0.69314718055994530942f

__device__ __forceinline__ float wave_red64(float v) {
#pragma unroll
    for (int off = 32; off > 0; off >>= 1) v += __shfl_down(v, off);
    return v;
}

__device__ __forceinline__ float sigmf(float x) { return 1.0f / (1.0f + expf(-x)); }

// Kernel 1: fused 4-way reduction over grad/param. Writes per-block partials
// (4 floats per block) to ws. Deterministic tree reduction, no atomics.
// signed-log sum is accumulated in log2 units; ln2 folded into final scaling.
__global__ __launch_bounds__(256) void lb_reduce(
    const float4* __restrict__ g4, const float4* __restrict__ p4,
    float* __restrict__ partials, int n4)
{
    float sg2 = 0.f, sp2 = 0.f, sgp = 0.f, ssl = 0.f;
    int stride = gridDim.x * blockDim.x;
    for (int i = blockIdx.x * blockDim.x + threadIdx.x; i < n4; i += stride) {
        float4 g = g4[i];
        float4 p = p4[i];
        sg2 = fmaf(g.x, g.x, fmaf(g.y, g.y, fmaf(g.z, g.z, fmaf(g.w, g.w, sg2))));
        sp2 = fmaf(p.x, p.x, fmaf(p.y, p.y, fmaf(p.z, p.z, fmaf(p.w, p.w, sp2))));
        sgp = fmaf(g.x, p.x, fmaf(g.y, p.y, fmaf(g.z, p.z, fmaf(g.w, p.w, sgp))));
        // sign(g)*log2(1+|g|)  (hardware v_log_f32; ln2 applied at the end)
        ssl += copysignf(__log2f(1.0f + fabsf(g.x)), g.x)
             + copysignf(__log2f(1.0f + fabsf(g.y)), g.y)
             + copysignf(__log2f(1.0f + fabsf(g.z)), g.z)
             + copysignf(__log2f(1.0f + fabsf(g.w)), g.w);
    }
    sg2 = wave_red64(sg2);
    sp2 = wave_red64(sp2);
    sgp = wave_red64(sgp);
    ssl = wave_red64(ssl);
    __shared__ float sh[4][4];
    int wid = threadIdx.x >> 6;
    if ((threadIdx.x & 63) == 0) {
        sh[0][wid] = sg2; sh[1][wid] = sp2; sh[2][wid] = sgp; sh[3][wid] = ssl;
    }
    __syncthreads();
    if (threadIdx.x == 0) {
        float* out = partials + (size_t)blockIdx.x * 4;
        out[0] = sh[0][0] + sh[0][1] + sh[0][2] + sh[0][3];
        out[1] = sh[1][0] + sh[1][1] + sh[1][2] + sh[1][3];
        out[2] = sh[2][0] + sh[2][1] + sh[2][2] + sh[2][3];
        out[3] = sh[3][0] + sh[3][1] + sh[3][2] + sh[3][3];
    }
}

// Kernel 2: single block. Reduce partials -> features -> LSTM cell -> heads -> mult.
__global__ __launch_bounds__(256) void lb_finish(
    const float* __restrict__ partials, int nblk,
    const float* __restrict__ neuromod, const float* __restrict__ comp_delta,
    const float* __restrict__ m_prev, const float* __restrict__ h_prev,
    const float* __restrict__ c_prev,
    const float* __restrict__ W_ih, const float* __restrict__ W_hh,
    const float* __restrict__ b_ih, const float* __restrict__ b_hh,
    const float* __restrict__ Ws, const float* __restrict__ bs,
    const float* __restrict__ Wg1, const float* __restrict__ bg1,
    const float* __restrict__ Wg2, const float* __restrict__ bg2,
    float* __restrict__ out, float sl_scale /* = ln2 / n */)
{
    __shared__ float feat[10];
    __shared__ float gates[4 * HID];
    __shared__ float hnew[HID];
    __shared__ float hidv[HID / 2];
    __shared__ float shred[4][4];

    // ---- reduce per-block partials ----
    float s0 = 0.f, s1 = 0.f, s2 = 0.f, s3 = 0.f;
    for (int i = threadIdx.x; i < nblk; i += blockDim.x) {
        const float* p = partials + (size_t)i * 4;
        s0 += p[0]; s1 += p[1]; s2 += p[2]; s3 += p[3];
    }
    s0 = wave_red64(s0); s1 = wave_red64(s1); s2 = wave_red64(s2); s3 = wave_red64(s3);
    int wid = threadIdx.x >> 6;
    if ((threadIdx.x & 63) == 0) {
        shred[0][wid] = s0; shred[1][wid] = s1; shred[2][wid] = s2; shred[3][wid] = s3;
    }
    __syncthreads();

    if (threadIdx.x == 0) {
        float sum_g2 = shred[0][0] + shred[0][1] + shred[0][2] + shred[0][3];
        float sum_p2 = shred[1][0] + shred[1][1] + shred[1][2] + shred[1][3];
        float sum_gp = shred[2][0] + shred[2][1] + shred[2][2] + shred[2][3];
        float sum_sl = shred[3][0] + shred[3][1] + shred[3][2] + shred[3][3];
        float g_norm = fmaxf(sqrtf(sum_g2), EPSF);
        float p_norm = fmaxf(sqrtf(sum_p2), EPSF);
        feat[0] = logf(g_norm + EPSF);
        feat[1] = logf(p_norm + EPSF);
        feat[2] = sum_gp / (g_norm * p_norm + EPSF);
        feat[3] = sum_sl * sl_scale;
        feat[4] = 0.9f * m_prev[0] + (1.0f - 0.9f) * g_norm;  // momentum
        feat[5] = comp_delta[0];
        feat[6] = neuromod[0];
        feat[7] = neuromod[1];
        feat[8] = neuromod[2];
        feat[9] = neuromod[3];
    }
    __syncthreads();

    // ---- LSTM gates: gates[r] = W_ih[r,:]@feat + b_ih[r] + W_hh[r,:]@h_prev + b_hh[r]
    if (threadIdx.x < 4 * HID) {
        int r = threadIdx.x;
        float acc = b_ih[r] + b_hh[r];
#pragma unroll
        for (int k = 0; k < 10; ++k) acc = fmaf(W_ih[r * 10 + k], feat[k], acc);
#pragma unroll
        for (int k = 0; k < HID; ++k) acc = fmaf(W_hh[r * HID + k], h_prev[k], acc);
        gates[r] = acc;
    }
    __syncthreads();

    // ---- cell/state update (torch gate order i, f, g, o) ----
    if (threadIdx.x < HID) {
        int j = threadIdx.x;
        float iv = sigmf(gates[j]);
        float fv = sigmf(gates[HID + j]);
        float gv = tanhf(gates[2 * HID + j]);
        float ov = sigmf(gates[3 * HID + j]);
        float c = fv * c_prev[j] + iv * gv;
        hnew[j] = ov * tanhf(c);
    }
    __syncthreads();

    // ---- gate head hidden layer ----
    if (threadIdx.x < HID / 2) {
        int k = threadIdx.x;
        float a = bg1[k];
#pragma unroll
        for (int j = 0; j < HID; ++j) a = fmaf(Wg1[k * HID + j], hnew[j], a);
        hidv[k] = tanhf(a);
    }
    __syncthreads();

    // ---- final heads + clip ----
    if (threadIdx.x == 0) {
        float rs = bs[0];
#pragma unroll
        for (int j = 0; j < HID; ++j) rs = fmaf(Ws[j], hnew[j], rs);
        float scale = expf(tanhf(rs));
        float cg = bg2[0];
#pragma unroll
        for (int k = 0; k < HID / 2; ++k) cg = fmaf(Wg2[k], hidv[k], cg);
        float comp_g = sigmf(cg);
        float mult = scale * (0.5f + comp_g);
        mult = fminf(fmaxf(mult, 0.01f), 10.0f);
        out[0] = mult;
    }
}

extern "C" void kernel_launch(void* const* d_in, const int* in_sizes, int n_in,
                              void* d_out, int out_size, void* d_ws, size_t ws_size,
                              hipStream_t stream) {
    const float* grad       = (const float*)d_in[0];
    const float* param      = (const float*)d_in[1];
    const float* neuromod   = (const float*)d_in[2];
    const float* comp_delta = (const float*)d_in[3];
    const float* m_prev     = (const float*)d_in[4];
    const float* h_prev     = (const float*)d_in[5];
    const float* c_prev     = (const float*)d_in[6];
    const float* W_ih       = (const float*)d_in[7];
    const float* W_hh       = (const float*)d_in[8];
    const float* b_ih       = (const float*)d_in[9];
    const float* b_hh       = (const float*)d_in[10];
    const float* Ws         = (const float*)d_in[11];
    const float* bs         = (const float*)d_in[12];
    const float* Wg1        = (const float*)d_in[13];
    const float* bg1        = (const float*)d_in[14];
    const float* Wg2        = (const float*)d_in[15];
    const float* bg2        = (const float*)d_in[16];

    int n = in_sizes[0];            // 33554432
    int n4 = n / 4;                 // float4 count

    int nblk = 2048;                // 2048 blocks * 256 thr -> full occupancy
    size_t need = (size_t)nblk * 4 * sizeof(float);
    if (ws_size < need) {
        nblk = (int)(ws_size / (4 * sizeof(float)));
        if (nblk < 1) nblk = 1;
    }
    float* partials = (float*)d_ws;

    lb_reduce<<<nblk, 256, 0, stream>>>((const float4*)grad, (const float4*)param,
                                        partials, n4);
    lb_finish<<<1, 256, 0, stream>>>(partials, nblk,
                                     neuromod, comp_delta, m_prev, h_prev, c_prev,
                                     W_ih, W_hh, b_ih, b_hh, Ws, bs,
                                     Wg1, bg1, Wg2, bg2,
                                     (float*)d_out, LN2F / (float)n);
}